// Round 7
// baseline (411.725 us; speedup 1.0000x reference)
//
#include <hip/hip_runtime.h>
#include <math.h>

// NerfactoModel fused forward, MFMA version r10.
// r10 = r9 (restored r0 + setprio + NT stores; 240.4us) + two reg-neutral:
//   (a) packed-FP32 dir MLP: float2 ext-vector + elementwise_fma ->
//       v_pk_fma_f32 (dual-issue f32; scalar fmaf runs at half rate on CDNA).
//       Same op order -> bit-identical to r9's scalar version.
//   (b) nontemporal LOADS on streaming inputs (ray/dirs/cam_idx): keep L2
//       for the ht table (gathered 1024x/wave-tile) and app_emb.
// Register ledger note: VGPR_Count 84 (arch) + ~84 AGPR (96 persistent
// frags) = 168 of 170 budget at 3 waves/SIMD. ZERO loop-carried additions
// allowed -- every r5-r8 prefetch variant spilled on this exact cliff.

typedef short short8 __attribute__((ext_vector_type(8)));
typedef float f32x4 __attribute__((ext_vector_type(4)));
typedef float f32x4a __attribute__((ext_vector_type(4), aligned(4)));
typedef float f32x2a __attribute__((ext_vector_type(2), aligned(4)));
typedef float f32x2 __attribute__((ext_vector_type(2)));
typedef unsigned int uint;
typedef unsigned short ushort;

struct EncC { float rf[16]; };   // (RES[l]-1) as float

#define PY 2481   // 2654435761 % 4096
#define PZ 1941   // 805459861 % 4096

#define MFMA(A,B,C) __builtin_amdgcn_mfma_f32_16x16x32_bf16(A, B, C, 0, 0, 0)
#define SETPRIO(x) __builtin_amdgcn_s_setprio(x)

// ---- LDS layout (bytes) ----
#define W1_OFF   0        // dens_w1^T  64 x 40 bf16 (5120)
#define W3_OFF   5120     // dens_w3^T  16 x 72 bf16 (2304)
#define C3_OFF   7424     // col_w3^T   16 x 72 bf16 (2304)
#define DB1_OFF  9728     // f32 biases
#define DB2_OFF  9984
#define DB3_OFF  10240
#define CB1_OFF  10304
#define CB2_OFF  10560
#define CB3_OFF  10816
// staging-only region (freed after A-frag preload), reused by ACT:
#define W2_OFF   10848    // dens_w2^T  64 x 72 (9216)
#define C1_OFF   20064    // col_w1^T (permuted K) 64 x 72 (9216)
#define C2_OFF   29280    // col_w2^T   64 x 72 (9216)
#define ACT_OFF  10848    // 4 waves x 64 rows x 144 B = 36864
#define LDS_BYTES 47712

__device__ __forceinline__ uint bf16rne(float x) {
    uint u = __builtin_bit_cast(uint, x);
    return (u + 0x7fffu + ((u >> 16) & 1u)) >> 16;
}
// truncation pack: result = hi[31:16] | lo[31:16]>>16  (one v_perm_b32)
__device__ __forceinline__ uint pktr(float lo, float hi) {
    return __builtin_amdgcn_perm(__builtin_bit_cast(uint, hi),
                                 __builtin_bit_cast(uint, lo), 0x07060302u);
}

// writeback: relu + bf16 trunc-pack, in place (bias already in acc).
__device__ __forceinline__ void layer_wb(const f32x4* acc, char* rowp, int q) {
#pragma unroll
    for (int mt = 0; mt < 4; ++mt) {
        const f32x4 v = acc[mt];
        uint2 pw;
        pw.x = pktr(fmaxf(v[0], 0.f), fmaxf(v[1], 0.f));
        pw.y = pktr(fmaxf(v[2], 0.f), fmaxf(v[3], 0.f));
        *(uint2*)(rowp + mt*32 + q*8) = pw;
    }
}

// full 64->64 layer (K=64), A-frags persistent in registers, bias as C-init.
__device__ __forceinline__ void layer64(char* wact, const short8* aw,
                                        const char* biasp, int l15, int q) {
    const int q16 = q * 16;
    f32x4 bf[4];
#pragma unroll
    for (int mt = 0; mt < 4; ++mt)
        bf[mt] = *(const f32x4*)(biasp + mt*64 + q16);
    SETPRIO(1);
#pragma unroll
    for (int nt = 0; nt < 4; ++nt) {
        char* rowp = wact + (nt*16 + l15)*144;
        short8 b0 = *(const short8*)(rowp + q16);
        short8 b1 = *(const short8*)(rowp + 64 + q16);
        f32x4 acc[4];
#pragma unroll
        for (int mt = 0; mt < 4; ++mt) {
            f32x4 z = MFMA(aw[2*mt], b0, bf[mt]);
            acc[mt] = MFMA(aw[2*mt + 1], b1, z);
        }
        layer_wb(acc, rowp, q);
    }
    SETPRIO(0);
}

__global__ __launch_bounds__(256, 3)
void nerf_mfma(const float* __restrict__ ray, const float* __restrict__ dirs,
               const int* __restrict__ cam_idx, const float* __restrict__ aabb,
               const float* __restrict__ ht,
               const float* __restrict__ dir_w1, const float* __restrict__ dir_b1,
               const float* __restrict__ dir_w2, const float* __restrict__ dir_b2,
               const float* __restrict__ dens_w1, const float* __restrict__ dens_b1,
               const float* __restrict__ dens_w2, const float* __restrict__ dens_b2,
               const float* __restrict__ dens_w3, const float* __restrict__ dens_b3,
               const float* __restrict__ col_w1, const float* __restrict__ col_b1,
               const float* __restrict__ col_w2, const float* __restrict__ col_b2,
               const float* __restrict__ col_w3, const float* __restrict__ col_b3,
               const float* __restrict__ app_emb,
               float* __restrict__ out, int n, EncC enc)
{
    __shared__ __align__(16) char smem[LDS_BYTES];
    const int t = threadIdx.x;

    // ---- zero weight staging area (pad slots must read as 0) ----
    {
        uint* z = (uint*)smem;
        for (int i = t; i < 38496/4; i += 256) z[i] = 0;
    }
    __syncthreads();
    // ---- stage weights: bf16 (RNE, once per block), transposed [out][in] ----
    {
        ushort* w1t = (ushort*)(smem + W1_OFF);
        for (int e = t; e < 2048; e += 256) w1t[(e&63)*40 + (e>>6)] = (ushort)bf16rne(dens_w1[e]);
        ushort* w2t = (ushort*)(smem + W2_OFF);
        for (int e = t; e < 4096; e += 256) w2t[(e&63)*72 + (e>>6)] = (ushort)bf16rne(dens_w2[e]);
        ushort* w3t = (ushort*)(smem + W3_OFF);
        for (int e = t; e < 1024; e += 256) w3t[(e&15)*72 + (e>>4)] = (ushort)bf16rne(dens_w3[e]);
        ushort* c1t = (ushort*)(smem + C1_OFF);
        for (int e = t; e < 4032; e += 256) {
            int in = e >> 6, o = e & 63;
            int pk = (in < 15) ? (in + 49) : ((in < 31) ? (in + 17) : (in - 31));
            c1t[o*72 + pk] = (ushort)bf16rne(col_w1[e]);
        }
        ushort* c2t = (ushort*)(smem + C2_OFF);
        for (int e = t; e < 4096; e += 256) c2t[(e&63)*72 + (e>>6)] = (ushort)bf16rne(col_w2[e]);
        ushort* c3t = (ushort*)(smem + C3_OFF);
        for (int e = t; e < 192; e += 256) c3t[(e%3)*72 + (e/3)] = (ushort)bf16rne(col_w3[e]);
        if (t < 64) {
            *(float*)(smem + DB1_OFF + t*4) = dens_b1[t];
            *(float*)(smem + DB2_OFF + t*4) = dens_b2[t];
            *(float*)(smem + CB1_OFF + t*4) = col_b1[t];
            *(float*)(smem + CB2_OFF + t*4) = col_b2[t];
        }
        if (t < 16) *(float*)(smem + DB3_OFF + t*4) = dens_b3[t];
        if (t < 4)  *(float*)(smem + CB3_OFF + t*4) = (t < 3) ? col_b3[t] : 0.f;
    }
    __syncthreads();

    const int w = t >> 6, lane = t & 63, l15 = lane & 15, q = lane >> 4;
    const int q16 = q * 16;
    char* wact = smem + ACT_OFF + w*9216;

    // ---- preload persistent A-frags for the three 64x64 layers (96 VGPRs) ----
    short8 aD2[8], aC1[8], aC2[8];
#pragma unroll
    for (int mt = 0; mt < 4; ++mt)
#pragma unroll
        for (int kk = 0; kk < 2; ++kk) {
            const int ro = (mt*16 + l15)*144 + kk*64 + q16;
            aD2[mt*2+kk] = *(const short8*)(smem + W2_OFF + ro);
            aC1[mt*2+kk] = *(const short8*)(smem + C1_OFF + ro);
            aC2[mt*2+kk] = *(const short8*)(smem + C2_OFF + ro);
        }
    __syncthreads();   // staging area now reusable as act buffers

    const float a0x = aabb[0], a0y = aabb[1], a0z = aabb[2];
    const float ivx = 1.f/(aabb[3]-a0x), ivy = 1.f/(aabb[4]-a0y), ivz = 1.f/(aabb[5]-a0z);

    const int ntiles = (n + 255) >> 8;
    for (int tile = blockIdx.x; tile < ntiles; tile += gridDim.x) {
        const int base = tile*256 + w*64;
        if (base >= n) continue;               // wave-uniform
        const bool full = (base + 64 <= n);    // wave-uniform (true for n%64==0)
        const int sc = full ? (base + lane) : min(base + lane, n - 1);
        float* otile = out + (size_t)base * 19;

        // ---- hash encoding -> act feats 0..31 (NT loads: streaming input) ----
        const float rx = __builtin_nontemporal_load(ray + 3*sc);
        const float ry = __builtin_nontemporal_load(ray + 3*sc + 1);
        const float rz = __builtin_nontemporal_load(ray + 3*sc + 2);
        float px = fminf(fmaxf((rx - a0x)*ivx, 0.f), 1.f);
        float py = fminf(fmaxf((ry - a0y)*ivy, 0.f), 1.f);
        float pz = fminf(fmaxf((rz - a0z)*ivz, 0.f), 1.f);
        uint encp[16];
#pragma unroll
        for (int l = 0; l < 16; ++l) {
            const float rf = enc.rf[l];
            const int cx = (int)(px*rf), cy = (int)(py*rf), cz = (int)(pz*rf);
            const int h = (cx + cy*PY + cz*PZ) & 4095;
            const float2 f = *(const float2*)(ht + (((l<<12) + h) << 1));
            encp[l] = pktr(f.x, f.y);
        }
        uint4* arow = (uint4*)(wact + lane*144);
        arow[0] = make_uint4(encp[0],  encp[1],  encp[2],  encp[3]);
        arow[1] = make_uint4(encp[4],  encp[5],  encp[6],  encp[7]);
        arow[2] = make_uint4(encp[8],  encp[9],  encp[10], encp[11]);
        arow[3] = make_uint4(encp[12], encp[13], encp[14], encp[15]);

        // ---- dens1: 32 -> 64, relu (K=32), bias as C-init ----
        {
            short8 a1[4];
            f32x4 bf[4];
#pragma unroll
            for (int mt = 0; mt < 4; ++mt) {
                a1[mt] = *(const short8*)(smem + W1_OFF + (mt*16 + l15)*80 + q16);
                bf[mt] = *(const f32x4*)(smem + DB1_OFF + mt*64 + q16);
            }
            SETPRIO(1);
#pragma unroll
            for (int nt = 0; nt < 4; ++nt) {
                char* rowp = wact + (nt*16 + l15)*144;
                short8 b = *(const short8*)(rowp + q16);
                f32x4 acc[4];
#pragma unroll
                for (int mt = 0; mt < 4; ++mt)
                    acc[mt] = MFMA(a1[mt], b, bf[mt]);
                layer_wb(acc, rowp, q);
            }
            SETPRIO(0);
        }
        // ---- dens2: 64 -> 64, relu ----
        layer64(wact, aD2, smem + DB2_OFF, l15, q);
        // ---- dens3: 64 -> 16 ; density+geo out, geo -> cin slots 49..63 ----
        {
            short8 a0 = *(const short8*)(smem + W3_OFF + l15*144 + q16);
            short8 a1 = *(const short8*)(smem + W3_OFF + l15*144 + 64 + q16);
            f32x4 bb3 = *(const f32x4*)(smem + DB3_OFF + q16);
            SETPRIO(1);
#pragma unroll
            for (int nt = 0; nt < 4; ++nt) {
                char* rowp = wact + (nt*16 + l15)*144;
                short8 b0 = *(const short8*)(rowp + q16);
                short8 b1 = *(const short8*)(rowp + 64 + q16);
                f32x4 z = MFMA(a0, b0, bb3);
                f32x4 v = MFMA(a1, b1, z);
                // geo slots: q0 writes [pad=0, g49, g50, g51]; q>0 writes 4 geo
                uint2 g;
                g.x = pktr(q == 0 ? 0.f : v[0], v[1]);
                g.y = pktr(v[2], v[3]);
                *(uint2*)(rowp + 96 + 8*q) = g;
                if (q == 0) v[0] = fmaxf(v[0], 0.f);   // density relu
                const int sg = nt*16 + l15;
                if (full || base + sg < n)
                    __builtin_nontemporal_store(v, (f32x4a*)(otile + sg*19 + 3 + q16/4));
            }
            SETPRIO(0);
        }
        // ---- per-lane: dir MLP (packed f32: v_pk_fma_f32) + app gather -> cin ----
        {
            const float dx = __builtin_nontemporal_load(dirs + 3*sc);
            const float dy = __builtin_nontemporal_load(dirs + 3*sc + 1);
            const float dz = __builtin_nontemporal_load(dirs + 3*sc + 2);
            const f32x2 dxv = {dx, dx}, dyv = {dy, dy}, dzv = {dz, dz};
            const f32x2 zz = {0.f, 0.f};
            f32x2 e1v[8];
#pragma unroll
            for (int j = 0; j < 8; ++j) {
                const f32x2 w0 = *(const f32x2a*)(dir_w1 + 2*j);
                const f32x2 w1v = *(const f32x2a*)(dir_w1 + 16 + 2*j);
                const f32x2 w2v = *(const f32x2a*)(dir_w1 + 32 + 2*j);
                const f32x2 bv = *(const f32x2a*)(dir_b1 + 2*j);
                f32x2 a = __builtin_elementwise_fma(dzv, w2v, bv);
                a = __builtin_elementwise_fma(dyv, w1v, a);
                a = __builtin_elementwise_fma(dxv, w0, a);
                e1v[j] = __builtin_elementwise_max(a, zz);
            }
            f32x2 ed2[8];
#pragma unroll
            for (int j = 0; j < 8; ++j) ed2[j] = *(const f32x2a*)(dir_b2 + 2*j);
#pragma unroll
            for (int i = 0; i < 16; ++i) {
                const float e = e1v[i >> 1][i & 1];
                const f32x2 ev = {e, e};
#pragma unroll
                for (int j = 0; j < 8; ++j)
                    ed2[j] = __builtin_elementwise_fma(ev,
                                *(const f32x2a*)(dir_w2 + i*16 + 2*j), ed2[j]);
            }
            const int cam = __builtin_nontemporal_load(cam_idx + sc);
            const float4* ap = (const float4*)(app_emb + (size_t)cam*32);
            uint pk[16];
#pragma unroll
            for (int qd = 0; qd < 8; ++qd) {
                const float4 vv = ap[qd];
                pk[2*qd]   = pktr(vv.x, vv.y);
                pk[2*qd+1] = pktr(vv.z, vv.w);
            }
            arow[0] = make_uint4(pk[0],  pk[1],  pk[2],  pk[3]);   // app 0..31
            arow[1] = make_uint4(pk[4],  pk[5],  pk[6],  pk[7]);
            arow[2] = make_uint4(pk[8],  pk[9],  pk[10], pk[11]);
            arow[3] = make_uint4(pk[12], pk[13], pk[14], pk[15]);
            uint ep[8];
#pragma unroll
            for (int j = 0; j < 8; ++j) ep[j] = pktr(ed2[j][0], ed2[j][1]);
            arow[4] = make_uint4(ep[0], ep[1], ep[2], ep[3]);      // edir 32..47
            arow[5] = make_uint4(ep[4], ep[5], ep[6], ep[7]);
        }
        // ---- col1, col2: 64 -> 64, relu ----
        layer64(wact, aC1, smem + CB1_OFF, l15, q);
        layer64(wact, aC2, smem + CB2_OFF, l15, q);
        // ---- col3: 64 -> 3 (rows 0..2), sigmoid ----
        {
            short8 a0 = *(const short8*)(smem + C3_OFF + l15*144 + q16);
            short8 a1 = *(const short8*)(smem + C3_OFF + l15*144 + 64 + q16);
            f32x4 bbc = *(const f32x4*)(smem + CB3_OFF);
            SETPRIO(1);
#pragma unroll
            for (int nt = 0; nt < 4; ++nt) {
                char* rowp = wact + (nt*16 + l15)*144;
                short8 b0 = *(const short8*)(rowp + q16);
                short8 b1 = *(const short8*)(rowp + 64 + q16);
                f32x4 z = MFMA(a0, b0, bbc);
                f32x4 v = MFMA(a1, b1, z);
                const int sg = nt*16 + l15;
                if (q == 0 && (full || base + sg < n)) {
                    float* op = otile + sg*19;
                    f32x2a r01;
                    r01[0] = 1.f / (1.f + __expf(-v[0]));
                    r01[1] = 1.f / (1.f + __expf(-v[1]));
                    __builtin_nontemporal_store(r01, (f32x2a*)op);
                    __builtin_nontemporal_store(1.f / (1.f + __expf(-v[2])), op + 2);
                }
            }
            SETPRIO(0);
        }
    }
}

extern "C" void kernel_launch(void* const* d_in, const int* in_sizes, int n_in,
                              void* d_out, int out_size, void* d_ws, size_t ws_size,
                              hipStream_t stream)
{
    const float* ray  = (const float*)d_in[0];
    const float* dirs = (const float*)d_in[1];
    const int*   cam  = (const int*)  d_in[2];
    const float* aabb = (const float*)d_in[3];
    const float* ht   = (const float*)d_in[4];
    const float* dw1  = (const float*)d_in[5];
    const float* db1  = (const float*)d_in[6];
    const float* dw2  = (const float*)d_in[7];
    const float* db2  = (const float*)d_in[8];
    const float* nw1  = (const float*)d_in[9];
    const float* nb1  = (const float*)d_in[10];
    const float* nw2  = (const float*)d_in[11];
    const float* nb2  = (const float*)d_in[12];
    const float* nw3  = (const float*)d_in[13];
    const float* nb3  = (const float*)d_in[14];
    const float* cw1  = (const float*)d_in[15];
    const float* cb1  = (const float*)d_in[16];
    const float* cw2  = (const float*)d_in[17];
    const float* cb2  = (const float*)d_in[18];
    const float* cw3  = (const float*)d_in[19];
    const float* cb3  = (const float*)d_in[20];
    const float* app  = (const float*)d_in[21];
    float* out = (float*)d_out;

    const int n = in_sizes[0] / 3;

    // Reproduce Python's RES (same libm): GROWTH = exp((ln2048-ln16)/15)
    EncC enc;
    const double growth = exp((log(2048.0) - log(16.0)) / 15.0);
    for (int i = 0; i < 16; ++i) {
        const int r = (int)(16.0 * pow(growth, (double)i));
        enc.rf[i] = (float)(r - 1);
    }

    const int ntiles = (n + 255) / 256;
    const int grid = ntiles < 768 ? ntiles : 768;
    nerf_mfma<<<grid, 256, 0, stream>>>(
        ray, dirs, cam, aabb, ht,
        dw1, db1, dw2, db2,
        nw1, nb1, nw2, nb2, nw3, nb3,
        cw1, cb1, cw2, cb2, cw3, cb3,
        app, out, n, enc);
}

// Round 8
// 399.547 us; speedup vs baseline: 1.0305x; 1.0305x over previous
//
#include <hip/hip_runtime.h>
#include <math.h>

// NerfactoModel fused forward, MFMA version r11.
// r11 = r9 (240.4us: r0 + setprio + NT stores) + edir-as-MFMA, done WITHOUT
//       extra act scratch (r5-r8's poison):
//   - e1 (16 bf16) staged into the act row's DEAD bytes 0..31 (features
//     0..15 die after dens3's b-reads; app overwrites them later anyway)
//   - dir_w2^T A-frag zero-padded k>=16 in 1KB persistent LDS, 1 read/tile
//   - dir_b2 as MFMA C-init; lanes q>=2 read old-act garbage but A=0 there
//   - removes ~265 VALU inst/lane/tile (the 256-FMA serial ed-loop)
//   r10 post-mortem: v_pk_fma_f32 is NOT 2x on CDNA4 (157.3TF is scalar
//   rate); NT loads hurt shared-cacheline streaming reads. Both reverted.
// Register ledger: 84 arch VGPR + 96 AGPR frags = 168/170 at 3 waves/SIMD.
// ZERO loop-carried additions allowed (r5-r8 cliff).

typedef short short8 __attribute__((ext_vector_type(8)));
typedef float f32x4 __attribute__((ext_vector_type(4)));
typedef float f32x4a __attribute__((ext_vector_type(4), aligned(4)));
typedef float f32x2a __attribute__((ext_vector_type(2), aligned(4)));
typedef unsigned int uint;
typedef unsigned short ushort;

struct EncC { float rf[16]; };   // (RES[l]-1) as float

#define PY 2481   // 2654435761 % 4096
#define PZ 1941   // 805459861 % 4096

#define MFMA(A,B,C) __builtin_amdgcn_mfma_f32_16x16x32_bf16(A, B, C, 0, 0, 0)
#define SETPRIO(x) __builtin_amdgcn_s_setprio(x)

// ---- LDS layout (bytes) ----
#define W1_OFF   0        // dens_w1^T  64 x 40 bf16 (5120)
#define W3_OFF   5120     // dens_w3^T  16 x 72 bf16 (2304)
#define C3_OFF   7424     // col_w3^T   16 x 72 bf16 (2304)
#define DB1_OFF  9728     // f32 biases
#define DB2_OFF  9984
#define DB3_OFF  10240
#define CB1_OFF  10304
#define CB2_OFF  10560
#define CB3_OFF  10816
#define DBE_OFF  10880    // dir_b2 f32 (64B)
#define AEP_OFF  10944    // dir_w2^T A-frag, persistent (64 lanes x 16B)
// staging-only region (freed after A-frag preload), reused by ACT:
#define W2_OFF   11968    // dens_w2^T  64 x 72 (9216)
#define C1_OFF   21184    // col_w1^T (permuted K) 64 x 72 (9216)
#define C2_OFF   30400    // col_w2^T   64 x 72 (9216)  -> staging ends 39616
#define ACT_OFF  11968    // 4 waves x 64 rows x 144 B = 36864
#define LDS_BYTES 48832

__device__ __forceinline__ uint bf16rne(float x) {
    uint u = __builtin_bit_cast(uint, x);
    return (u + 0x7fffu + ((u >> 16) & 1u)) >> 16;
}
// truncation pack: result = hi[31:16] | lo[31:16]>>16  (one v_perm_b32)
__device__ __forceinline__ uint pktr(float lo, float hi) {
    return __builtin_amdgcn_perm(__builtin_bit_cast(uint, hi),
                                 __builtin_bit_cast(uint, lo), 0x07060302u);
}

// writeback: relu + bf16 trunc-pack, in place (bias already in acc).
__device__ __forceinline__ void layer_wb(const f32x4* acc, char* rowp, int q) {
#pragma unroll
    for (int mt = 0; mt < 4; ++mt) {
        const f32x4 v = acc[mt];
        uint2 pw;
        pw.x = pktr(fmaxf(v[0], 0.f), fmaxf(v[1], 0.f));
        pw.y = pktr(fmaxf(v[2], 0.f), fmaxf(v[3], 0.f));
        *(uint2*)(rowp + mt*32 + q*8) = pw;
    }
}

// full 64->64 layer (K=64), A-frags persistent in registers, bias as C-init.
__device__ __forceinline__ void layer64(char* wact, const short8* aw,
                                        const char* biasp, int l15, int q) {
    const int q16 = q * 16;
    f32x4 bf[4];
#pragma unroll
    for (int mt = 0; mt < 4; ++mt)
        bf[mt] = *(const f32x4*)(biasp + mt*64 + q16);
    SETPRIO(1);
#pragma unroll
    for (int nt = 0; nt < 4; ++nt) {
        char* rowp = wact + (nt*16 + l15)*144;
        short8 b0 = *(const short8*)(rowp + q16);
        short8 b1 = *(const short8*)(rowp + 64 + q16);
        f32x4 acc[4];
#pragma unroll
        for (int mt = 0; mt < 4; ++mt) {
            f32x4 z = MFMA(aw[2*mt], b0, bf[mt]);
            acc[mt] = MFMA(aw[2*mt + 1], b1, z);
        }
        layer_wb(acc, rowp, q);
    }
    SETPRIO(0);
}

__global__ __launch_bounds__(256, 3)
void nerf_mfma(const float* __restrict__ ray, const float* __restrict__ dirs,
               const int* __restrict__ cam_idx, const float* __restrict__ aabb,
               const float* __restrict__ ht,
               const float* __restrict__ dir_w1, const float* __restrict__ dir_b1,
               const float* __restrict__ dir_w2, const float* __restrict__ dir_b2,
               const float* __restrict__ dens_w1, const float* __restrict__ dens_b1,
               const float* __restrict__ dens_w2, const float* __restrict__ dens_b2,
               const float* __restrict__ dens_w3, const float* __restrict__ dens_b3,
               const float* __restrict__ col_w1, const float* __restrict__ col_b1,
               const float* __restrict__ col_w2, const float* __restrict__ col_b2,
               const float* __restrict__ col_w3, const float* __restrict__ col_b3,
               const float* __restrict__ app_emb,
               float* __restrict__ out, int n, EncC enc)
{
    __shared__ __align__(16) char smem[LDS_BYTES];
    const int t = threadIdx.x;

    // ---- zero head + staging area (pad slots / aE zero-rows must read 0) ----
    {
        uint* z = (uint*)smem;
        for (int i = t; i < 39616/4; i += 256) z[i] = 0;
    }
    __syncthreads();
    // ---- stage weights: bf16 (RNE, once per block), transposed [out][in] ----
    {
        ushort* w1t = (ushort*)(smem + W1_OFF);
        for (int e = t; e < 2048; e += 256) w1t[(e&63)*40 + (e>>6)] = (ushort)bf16rne(dens_w1[e]);
        ushort* w2t = (ushort*)(smem + W2_OFF);
        for (int e = t; e < 4096; e += 256) w2t[(e&63)*72 + (e>>6)] = (ushort)bf16rne(dens_w2[e]);
        ushort* w3t = (ushort*)(smem + W3_OFF);
        for (int e = t; e < 1024; e += 256) w3t[(e&15)*72 + (e>>4)] = (ushort)bf16rne(dens_w3[e]);
        ushort* c1t = (ushort*)(smem + C1_OFF);
        for (int e = t; e < 4032; e += 256) {
            int in = e >> 6, o = e & 63;
            int pk = (in < 15) ? (in + 49) : ((in < 31) ? (in + 17) : (in - 31));
            c1t[o*72 + pk] = (ushort)bf16rne(col_w1[e]);
        }
        ushort* c2t = (ushort*)(smem + C2_OFF);
        for (int e = t; e < 4096; e += 256) c2t[(e&63)*72 + (e>>6)] = (ushort)bf16rne(col_w2[e]);
        ushort* c3t = (ushort*)(smem + C3_OFF);
        for (int e = t; e < 192; e += 256) c3t[(e%3)*72 + (e/3)] = (ushort)bf16rne(col_w3[e]);
        // dir_w2^T A-frag rows 0..31 (q<2); rows 32..63 stay zero (zero-pass)
        if (t < 256) {
            const int li = t >> 3, j = t & 7;           // li 0..31, j 0..7
            *(ushort*)(smem + AEP_OFF + li*16 + j*2) =
                (ushort)bf16rne(dir_w2[((li >> 4)*8 + j)*16 + (li & 15)]);
        }
        if (t < 64) {
            *(float*)(smem + DB1_OFF + t*4) = dens_b1[t];
            *(float*)(smem + DB2_OFF + t*4) = dens_b2[t];
            *(float*)(smem + CB1_OFF + t*4) = col_b1[t];
            *(float*)(smem + CB2_OFF + t*4) = col_b2[t];
        }
        if (t < 16) *(float*)(smem + DB3_OFF + t*4) = dens_b3[t];
        if (t < 16) *(float*)(smem + DBE_OFF + t*4) = dir_b2[t];
        if (t < 4)  *(float*)(smem + CB3_OFF + t*4) = (t < 3) ? col_b3[t] : 0.f;
    }
    __syncthreads();

    const int w = t >> 6, lane = t & 63, l15 = lane & 15, q = lane >> 4;
    const int q16 = q * 16;
    char* wact = smem + ACT_OFF + w*9216;

    // ---- preload persistent A-frags for the three 64x64 layers (96 VGPRs) ----
    short8 aD2[8], aC1[8], aC2[8];
#pragma unroll
    for (int mt = 0; mt < 4; ++mt)
#pragma unroll
        for (int kk = 0; kk < 2; ++kk) {
            const int ro = (mt*16 + l15)*144 + kk*64 + q16;
            aD2[mt*2+kk] = *(const short8*)(smem + W2_OFF + ro);
            aC1[mt*2+kk] = *(const short8*)(smem + C1_OFF + ro);
            aC2[mt*2+kk] = *(const short8*)(smem + C2_OFF + ro);
        }
    __syncthreads();   // staging area now reusable as act buffers

    const float a0x = aabb[0], a0y = aabb[1], a0z = aabb[2];
    const float ivx = 1.f/(aabb[3]-a0x), ivy = 1.f/(aabb[4]-a0y), ivz = 1.f/(aabb[5]-a0z);

    const int ntiles = (n + 255) >> 8;
    for (int tile = blockIdx.x; tile < ntiles; tile += gridDim.x) {
        const int base = tile*256 + w*64;
        if (base >= n) continue;               // wave-uniform
        const bool full = (base + 64 <= n);    // wave-uniform (true for n%64==0)
        const int sc = full ? (base + lane) : min(base + lane, n - 1);
        float* otile = out + (size_t)base * 19;

        // ---- hash encoding -> act feats 0..31 ----
        float px = fminf(fmaxf((ray[3*sc  ] - a0x)*ivx, 0.f), 1.f);
        float py = fminf(fmaxf((ray[3*sc+1] - a0y)*ivy, 0.f), 1.f);
        float pz = fminf(fmaxf((ray[3*sc+2] - a0z)*ivz, 0.f), 1.f);
        uint encp[16];
#pragma unroll
        for (int l = 0; l < 16; ++l) {
            const float rf = enc.rf[l];
            const int cx = (int)(px*rf), cy = (int)(py*rf), cz = (int)(pz*rf);
            const int h = (cx + cy*PY + cz*PZ) & 4095;
            const float2 f = *(const float2*)(ht + (((l<<12) + h) << 1));
            encp[l] = pktr(f.x, f.y);
        }
        uint4* arow = (uint4*)(wact + lane*144);
        arow[0] = make_uint4(encp[0],  encp[1],  encp[2],  encp[3]);
        arow[1] = make_uint4(encp[4],  encp[5],  encp[6],  encp[7]);
        arow[2] = make_uint4(encp[8],  encp[9],  encp[10], encp[11]);
        arow[3] = make_uint4(encp[12], encp[13], encp[14], encp[15]);

        // ---- dens1: 32 -> 64, relu (K=32), bias as C-init ----
        {
            short8 a1[4];
            f32x4 bf[4];
#pragma unroll
            for (int mt = 0; mt < 4; ++mt) {
                a1[mt] = *(const short8*)(smem + W1_OFF + (mt*16 + l15)*80 + q16);
                bf[mt] = *(const f32x4*)(smem + DB1_OFF + mt*64 + q16);
            }
            SETPRIO(1);
#pragma unroll
            for (int nt = 0; nt < 4; ++nt) {
                char* rowp = wact + (nt*16 + l15)*144;
                short8 b = *(const short8*)(rowp + q16);
                f32x4 acc[4];
#pragma unroll
                for (int mt = 0; mt < 4; ++mt)
                    acc[mt] = MFMA(a1[mt], b, bf[mt]);
                layer_wb(acc, rowp, q);
            }
            SETPRIO(0);
        }
        // ---- dens2: 64 -> 64, relu ----
        layer64(wact, aD2, smem + DB2_OFF, l15, q);
        // ---- dens3: 64 -> 16 ; density+geo out, geo -> cin slots 49..63 ----
        {
            short8 a0 = *(const short8*)(smem + W3_OFF + l15*144 + q16);
            short8 a1 = *(const short8*)(smem + W3_OFF + l15*144 + 64 + q16);
            f32x4 bb3 = *(const f32x4*)(smem + DB3_OFF + q16);
            SETPRIO(1);
#pragma unroll
            for (int nt = 0; nt < 4; ++nt) {
                char* rowp = wact + (nt*16 + l15)*144;
                short8 b0 = *(const short8*)(rowp + q16);
                short8 b1 = *(const short8*)(rowp + 64 + q16);
                f32x4 z = MFMA(a0, b0, bb3);
                f32x4 v = MFMA(a1, b1, z);
                // geo slots: q0 writes [pad=0, g49, g50, g51]; q>0 writes 4 geo
                uint2 g;
                g.x = pktr(q == 0 ? 0.f : v[0], v[1]);
                g.y = pktr(v[2], v[3]);
                *(uint2*)(rowp + 96 + 8*q) = g;
                if (q == 0) v[0] = fmaxf(v[0], 0.f);   // density relu
                const int sg = nt*16 + l15;
                if (full || base + sg < n)
                    __builtin_nontemporal_store(v, (f32x4a*)(otile + sg*19 + 3 + q16/4));
            }
            SETPRIO(0);
        }
        // ---- e1 = relu(dirs@w1+b1) fp32 scalar; pack into DEAD act bytes 0..31 ----
        {
            const float dx = dirs[3*sc], dy = dirs[3*sc+1], dz = dirs[3*sc+2];
            float e1[16];
#pragma unroll
            for (int j = 0; j < 16; ++j)
                e1[j] = fmaxf(fmaf(dx, dir_w1[j],
                              fmaf(dy, dir_w1[16+j],
                              fmaf(dz, dir_w1[32+j], dir_b1[j]))), 0.f);
            uint ep[8];
#pragma unroll
            for (int j = 0; j < 8; ++j) ep[j] = pktr(e1[2*j], e1[2*j+1]);
            arow[0] = make_uint4(ep[0], ep[1], ep[2], ep[3]);   // feats 0..7  <- e1
            arow[1] = make_uint4(ep[4], ep[5], ep[6], ep[7]);   // feats 8..15 <- e1
        }
        // ---- edir = e1 @ dir_w2 + b2 via 4 MFMAs -> cin feats 32..47 ----
        // A = dir_w2^T zero-padded (lanes q>=2 hold A=0, so their B garbage
        // [old act feats 16..31] contributes nothing). Bias via C-init.
        {
            const short8 aE = *(const short8*)(smem + AEP_OFF + lane*16);
            const f32x4 bbe = *(const f32x4*)(smem + DBE_OFF + q16);
            SETPRIO(1);
#pragma unroll
            for (int nt = 0; nt < 4; ++nt) {
                char* rowp = wact + (nt*16 + l15)*144;
                short8 b = *(const short8*)(rowp + q16);
                f32x4 v = MFMA(aE, b, bbe);
                uint2 pw;
                pw.x = pktr(v[0], v[1]);
                pw.y = pktr(v[2], v[3]);
                *(uint2*)(rowp + 64 + 8*q) = pw;    // feats 32+q*4 .. +3
            }
            SETPRIO(0);
        }
        // ---- app embedding -> cin feats 0..31 (overwrites e1 staging) ----
        {
            const int cam = cam_idx[sc];
            const float4* ap = (const float4*)(app_emb + (size_t)cam*32);
            uint pk[16];
#pragma unroll
            for (int qd = 0; qd < 8; ++qd) {
                const float4 vv = ap[qd];
                pk[2*qd]   = pktr(vv.x, vv.y);
                pk[2*qd+1] = pktr(vv.z, vv.w);
            }
            arow[0] = make_uint4(pk[0],  pk[1],  pk[2],  pk[3]);   // app 0..31
            arow[1] = make_uint4(pk[4],  pk[5],  pk[6],  pk[7]);
            arow[2] = make_uint4(pk[8],  pk[9],  pk[10], pk[11]);
            arow[3] = make_uint4(pk[12], pk[13], pk[14], pk[15]);
        }
        // ---- col1, col2: 64 -> 64, relu ----
        layer64(wact, aC1, smem + CB1_OFF, l15, q);
        layer64(wact, aC2, smem + CB2_OFF, l15, q);
        // ---- col3: 64 -> 3 (rows 0..2), sigmoid ----
        {
            short8 a0 = *(const short8*)(smem + C3_OFF + l15*144 + q16);
            short8 a1 = *(const short8*)(smem + C3_OFF + l15*144 + 64 + q16);
            f32x4 bbc = *(const f32x4*)(smem + CB3_OFF);
            SETPRIO(1);
#pragma unroll
            for (int nt = 0; nt < 4; ++nt) {
                char* rowp = wact + (nt*16 + l15)*144;
                short8 b0 = *(const short8*)(rowp + q16);
                short8 b1 = *(const short8*)(rowp + 64 + q16);
                f32x4 z = MFMA(a0, b0, bbc);
                f32x4 v = MFMA(a1, b1, z);
                const int sg = nt*16 + l15;
                if (q == 0 && (full || base + sg < n)) {
                    float* op = otile + sg*19;
                    f32x2a r01;
                    r01[0] = 1.f / (1.f + __expf(-v[0]));
                    r01[1] = 1.f / (1.f + __expf(-v[1]));
                    __builtin_nontemporal_store(r01, (f32x2a*)op);
                    __builtin_nontemporal_store(1.f / (1.f + __expf(-v[2])), op + 2);
                }
            }
            SETPRIO(0);
        }
    }
}

extern "C" void kernel_launch(void* const* d_in, const int* in_sizes, int n_in,
                              void* d_out, int out_size, void* d_ws, size_t ws_size,
                              hipStream_t stream)
{
    const float* ray  = (const float*)d_in[0];
    const float* dirs = (const float*)d_in[1];
    const int*   cam  = (const int*)  d_in[2];
    const float* aabb = (const float*)d_in[3];
    const float* ht   = (const float*)d_in[4];
    const float* dw1  = (const float*)d_in[5];
    const float* db1  = (const float*)d_in[6];
    const float* dw2  = (const float*)d_in[7];
    const float* db2  = (const float*)d_in[8];
    const float* nw1  = (const float*)d_in[9];
    const float* nb1  = (const float*)d_in[10];
    const float* nw2  = (const float*)d_in[11];
    const float* nb2  = (const float*)d_in[12];
    const float* nw3  = (const float*)d_in[13];
    const float* nb3  = (const float*)d_in[14];
    const float* cw1  = (const float*)d_in[15];
    const float* cb1  = (const float*)d_in[16];
    const float* cw2  = (const float*)d_in[17];
    const float* cb2  = (const float*)d_in[18];
    const float* cw3  = (const float*)d_in[19];
    const float* cb3  = (const float*)d_in[20];
    const float* app  = (const float*)d_in[21];
    float* out = (float*)d_out;

    const int n = in_sizes[0] / 3;

    // Reproduce Python's RES (same libm): GROWTH = exp((ln2048-ln16)/15)
    EncC enc;
    const double growth = exp((log(2048.0) - log(16.0)) / 15.0);
    for (int i = 0; i < 16; ++i) {
        const int r = (int)(16.0 * pow(growth, (double)i));
        enc.rf[i] = (float)(r - 1);
    }

    const int ntiles = (n + 255) / 256;
    const int grid = ntiles < 768 ? ntiles : 768;
    nerf_mfma<<<grid, 256, 0, stream>>>(
        ray, dirs, cam, aabb, ht,
        dw1, db1, dw2, db2,
        nw1, nb1, nw2, nb2, nw3, nb3,
        cw1, cb1, cw2, cb2, cw3, cb3,
        app, out, n, enc);
}